// Round 6
// baseline (282.745 us; speedup 1.0000x reference)
//
#include <hip/hip_runtime.h>

// DynamicFC: out[b,o,h,w] = sum_i w[b,o,i] * x[b,i,h,w] + bias[b,o]
// Batched GEMM per b: M=Cout=512, N=HW=784, K=Cin=512, fp32 in/out.
// R8 vs R7 (post-mortem: R6 vs R7 proved exposed global-load latency was
// NOT the bottleneck — counted-vmcnt barriers changed nothing. The cost is
// the barrier-locked staging chain itself: load+cvt+ds_write of BOTH tiles
// on every wave's synchronized path. m233: 2-phase overhead is structural):
//  - A (W matrix) LDS path DELETED. Waves own disjoint 32-row A-slices (no
//    inter-wave reuse); A-fragments are lane-row/k-contiguous -> 2x dwordx4
//    direct from global (L2-hot: per-XCD batch set W 1MB + X 1.6MB < 4MB),
//    converted in-register. Removes A's loads/writes/reads from the barrier
//    region and halves LDS (38.9 -> 18.5 KB).
//  - B keeps LDS (needs k-transpose + 4-wave sharing), R3 bank mapping.
//  - One raw s_barrier + lgkmcnt(0) per K-step; counted vmcnt only.
//  - Single-set prefetch for A and B, each ~one full K-step of flight,
//    WAR-clean: regs consumed (cvt/write) then immediately reloaded.

#define CIN  512
#define COUT 512
#define HW   784      // 28*28 = 7*112
#define BM   128
#define BN   112
#define BK   32
#define LSTR 40       // 32 + 8 pad bf16 (80B row; 16B-aligned rows)

typedef __bf16 bf16_t;
typedef __bf16 bf16x8 __attribute__((ext_vector_type(8)));
typedef __bf16 bf16x4 __attribute__((ext_vector_type(4)));
typedef float  f32x4  __attribute__((ext_vector_type(4)));

__device__ __forceinline__ bf16x8 pack8(f32x4 a, f32x4 b) {
    bf16x8 r;
    r[0] = (bf16_t)a[0]; r[1] = (bf16_t)a[1];
    r[2] = (bf16_t)a[2]; r[3] = (bf16_t)a[3];
    r[4] = (bf16_t)b[0]; r[5] = (bf16_t)b[1];
    r[6] = (bf16_t)b[2]; r[7] = (bf16_t)b[3];
    return r;
}

// lgkmcnt(0) (LDS visibility) + raw barrier. NO vmcnt drain: global loads
// stay in flight across the barrier.
#define BARRIER() do {                                        \
        __builtin_amdgcn_sched_barrier(0);                    \
        asm volatile("s_waitcnt lgkmcnt(0)" ::: "memory");    \
        __builtin_amdgcn_s_barrier();                         \
        __builtin_amdgcn_sched_barrier(0);                    \
    } while (0)

__global__ __launch_bounds__(256, 2) void dynfc_kernel(
    const float* __restrict__ x,     // [64][512][784]
    const float* __restrict__ w,     // [64][512][512]
    const float* __restrict__ bias,  // [64][512]
    float* __restrict__ out)         // [64][512][784]
{
    __shared__ bf16_t Bsm[2][BN * LSTR];   // 2 x 8.75 KB
    __shared__ float  bias_sm[BM];

    // XCD swizzle: whole batches per XCD so W+X re-reads hit that XCD's L2.
    const int bid   = blockIdx.x;        // 0..1791
    const int xcd   = bid & 7;
    const int j     = bid >> 3;          // 0..223
    const int batch = xcd + 8 * (j / 28);
    const int trem  = j % 28;            // 4 m-tiles * 7 n-tiles
    const int tm    = trem / 7;
    const int tn    = trem % 7;
    const int m0    = tm * BM;
    const int n0    = tn * BN;

    const int tid  = threadIdx.x;
    const int lane = tid & 63;
    const int wid  = tid >> 6;
    const int wm   = wid * 32;           // wave's 32-row slice
    const int l15  = lane & 15;
    const int quad = lane >> 4;

    const float* xb = x + (size_t)batch * CIN * HW;
    const float* wb = w + (size_t)batch * COUT * CIN;

    if (tid < 32) {
        f32x4 bv = *(const f32x4*)(bias + batch * COUT + m0 + tid * 4);
        *(f32x4*)&bias_sm[tid * 4] = bv;
    }

    // B staging (R3 mapping): kg = tid&7 (k-group of 4), ng = tid>>3 (col
    // group of 4). Write banks: 16 distinct, 4-way (~free).
    const int  kg      = tid & 7;        // 0..7
    const int  ng      = tid >> 3;       // 0..31
    const bool bactive = (ng < 28);      // 28*4 = 112 cols exactly

    const float* bsrc = xb + (size_t)(kg * 4) * HW + n0 + ng * 4;
    // A direct: this lane's fragment rows (frag i adds i*16 rows).
    const float* arow = wb + (size_t)(m0 + wm + l15) * CIN + quad * 8;

    f32x4 Ar[4];          // A in-flight: frag0 lo/hi, frag1 lo/hi
    f32x4 br[4];          // B in-flight: 4 k-rows x 4 cols

#define LOAD_A(t) do {                                                        \
        const float* ap_ = arow + (t) * BK;                                   \
        Ar[0] = *(const f32x4*)(ap_);                                         \
        Ar[1] = *(const f32x4*)(ap_ + 4);                                     \
        Ar[2] = *(const f32x4*)(ap_ + (size_t)16 * CIN);                      \
        Ar[3] = *(const f32x4*)(ap_ + (size_t)16 * CIN + 4);                  \
    } while (0)

#define LOAD_B(t) do {                                                        \
        if (bactive) {                                                        \
            const float* bp_ = bsrc + (size_t)((t) * BK) * HW;                \
            br[0] = *(const f32x4*)(bp_);                                     \
            br[1] = *(const f32x4*)(bp_ + HW);                                \
            br[2] = *(const f32x4*)(bp_ + 2 * HW);                            \
            br[3] = *(const f32x4*)(bp_ + 3 * HW);                            \
        }                                                                     \
    } while (0)

#define WRITE_B(s) do {                                                       \
        if (bactive) {                                                        \
            bf16_t* Bb_ = &Bsm[s][0];                                         \
            _Pragma("unroll")                                                 \
            for (int nn = 0; nn < 4; nn++) {                                  \
                bf16x4 c_;                                                    \
                c_[0] = (bf16_t)br[0][nn]; c_[1] = (bf16_t)br[1][nn];         \
                c_[2] = (bf16_t)br[2][nn]; c_[3] = (bf16_t)br[3][nn];         \
                *(bf16x4*)&Bb_[(ng * 4 + nn) * LSTR + kg * 4] = c_;           \
            }                                                                 \
        }                                                                     \
    } while (0)

    f32x4 acc[2][7] = {};

    // ---- prologue ----
    LOAD_B(0);
    LOAD_A(0);
    WRITE_B(0);           // counted vmcnt wait for br here
    LOAD_B(1);            // refill br for tile 1
    BARRIER();

    #pragma unroll
    for (int t = 0; t < 16; ++t) {
        const int s = t & 1;

        // ---- A(t): convert in-flight regs -> frags, then reissue A(t+1).
        // pack8 reads Ar (vmcnt wait), loads then overwrite (WAR, in order).
        bf16x8 afr[2];
        afr[0] = pack8(Ar[0], Ar[1]);
        afr[1] = pack8(Ar[2], Ar[3]);
        if (t + 1 < 16) LOAD_A(t + 1);
        __builtin_amdgcn_sched_barrier(0);

        // ---- B frags from buf[s] + MFMA ----
        {
            const bf16_t* Bb = &Bsm[s][0];
            bf16x8 bfr[7];
            #pragma unroll
            for (int j2 = 0; j2 < 7; j2++)
                bfr[j2] = *(const bf16x8*)&Bb[(j2 * 16 + l15) * LSTR + quad * 8];
            __builtin_amdgcn_s_setprio(1);
            #pragma unroll
            for (int i = 0; i < 2; i++)
                #pragma unroll
                for (int j2 = 0; j2 < 7; j2++)
                    acc[i][j2] = __builtin_amdgcn_mfma_f32_16x16x32_bf16(afr[i], bfr[j2], acc[i][j2], 0, 0, 0);
            __builtin_amdgcn_s_setprio(0);
        }
        __builtin_amdgcn_sched_barrier(0);

        // ---- B(t+1): cvt+write into other buffer; reissue B(t+2) ----
        if (t + 1 < 16) WRITE_B(s ^ 1);      // counted vmcnt wait for br
        if (t + 2 < 16) LOAD_B(t + 2);       // refill br (WAR after write)
        BARRIER();
    }

#undef LOAD_A
#undef LOAD_B
#undef WRITE_B

    // ---- epilogue: add bias, plain store (7*112 == 784, no guard) ----
    // C/D layout: col = lane&15, row = quad*4 + r
    float* ob = out + (size_t)batch * COUT * HW;
    #pragma unroll
    for (int j2 = 0; j2 < 7; j2++) {
        const int n = n0 + j2 * 16 + l15;
        #pragma unroll
        for (int i = 0; i < 2; i++) {
            #pragma unroll
            for (int r = 0; r < 4; r++) {
                const int m = wm + i * 16 + quad * 4 + r;
                ob[(size_t)(m0 + m) * HW + n] = acc[i][j2][r] + bias_sm[m];
            }
        }
    }
}

extern "C" void kernel_launch(void* const* d_in, const int* in_sizes, int n_in,
                              void* d_out, int out_size, void* d_ws, size_t ws_size,
                              hipStream_t stream) {
    (void)in_sizes; (void)n_in; (void)d_ws; (void)ws_size; (void)out_size;
    const float* x    = (const float*)d_in[0];
    const float* w    = (const float*)d_in[1];
    const float* bias = (const float*)d_in[2];
    float* out        = (float*)d_out;

    dim3 grid(64 * 4 * 7);   // 64 batches * 4 m-tiles * 7 n-tiles
    dim3 block(256);
    dynfc_kernel<<<grid, block, 0, stream>>>(x, w, bias, out);
}

// Round 7
// 258.370 us; speedup vs baseline: 1.0943x; 1.0943x over previous
//
#include <hip/hip_runtime.h>

// DynamicFC: out[b,o,h,w] = sum_i w[b,o,i] * x[b,i,h,w] + bias[b,o]
// Batched GEMM per b: M=Cout=512, N=HW=784, K=Cin=512, fp32 in/out.
// R9 vs R8 (arc post-mortem: R4-R8 all land 120-140us; VGPR never >104 ->
// compiler never funds in-flight staging; with launch_bounds(256,2) the
// machine runs ~1.6 waves/SIMD, so every exposed latency cycle is dead.
// ILP via source-level pipelining is a lost fight; hide latency with TLP):
//  - 512-thread blocks (8 waves), tile 256x112; per-wave datapath identical
//    to the proven R3 shape (32x112, 2x7 frags, 14 MFMA/step, acc 56).
//  - launch_bounds(512,4): VGPR cap 128 -> 4 waves/SIMD -> 16 waves/CU ->
//    2 co-resident blocks interleave: one computes while the other stages.
//  - Single-buffer LDS (~30 KB; 2 blocks = 60 KB < 160), plain syncthreads,
//    no sched_barriers, no dual register sets: simple 2-barrier loop.
//  - Grid 896 (64 batches x 2 m-tiles x 7 n-tiles): each X n-slice read by
//    2 blocks (was 4) -> less L2 pressure; 6 staging loads/thread/step.

#define CIN  512
#define COUT 512
#define HW   784      // 28*28 = 7*112
#define BM   256
#define BN   112
#define BK   32
#define LSTR 40       // 32 + 8 pad bf16 (80B row; 16B-aligned rows)

typedef __bf16 bf16_t;
typedef __bf16 bf16x8 __attribute__((ext_vector_type(8)));
typedef __bf16 bf16x2 __attribute__((ext_vector_type(2)));
typedef float  f32x4  __attribute__((ext_vector_type(4)));

__device__ __forceinline__ bf16x8 pack8(f32x4 a, f32x4 b) {
    bf16x8 r;
    r[0] = (bf16_t)a[0]; r[1] = (bf16_t)a[1];
    r[2] = (bf16_t)a[2]; r[3] = (bf16_t)a[3];
    r[4] = (bf16_t)b[0]; r[5] = (bf16_t)b[1];
    r[6] = (bf16_t)b[2]; r[7] = (bf16_t)b[3];
    return r;
}

__global__ __launch_bounds__(512, 4) void dynfc_kernel(
    const float* __restrict__ x,     // [64][512][784]
    const float* __restrict__ w,     // [64][512][512]
    const float* __restrict__ bias,  // [64][512]
    float* __restrict__ out)         // [64][512][784]
{
    __shared__ bf16_t Asm[BM * LSTR];   // 20 KB
    __shared__ bf16_t Bsm[BN * LSTR];   // 8.75 KB
    __shared__ float  bias_sm[BM];      // 1 KB

    // XCD swizzle: whole batches per XCD so W+X re-reads hit that XCD's L2.
    const int bid   = blockIdx.x;        // 0..895
    const int xcd   = bid & 7;
    const int j     = bid >> 3;          // 0..111
    const int batch = xcd + 8 * (j / 14);
    const int trem  = j % 14;            // 2 m-tiles * 7 n-tiles
    const int tm    = trem / 7;
    const int tn    = trem % 7;
    const int m0    = tm * BM;
    const int n0    = tn * BN;

    const int tid  = threadIdx.x;        // 0..511
    const int lane = tid & 63;
    const int wid  = tid >> 6;           // 0..7
    const int wm   = wid * 32;           // wave's 32-row slice of 256
    const int l15  = lane & 15;
    const int quad = lane >> 4;

    const float* xb = x + (size_t)batch * CIN * HW;
    const float* wb = w + (size_t)batch * COUT * CIN;

    if (tid < 64) {
        f32x4 bv = *(const f32x4*)(bias + batch * COUT + m0 + tid * 4);
        *(f32x4*)&bias_sm[tid * 4] = bv;
    }

    // A staging: thread -> (row ar of 256, k-half ah of {0,16}); 16 fp32.
    const int ar = tid >> 1;             // 0..255
    const int ah = (tid & 1) * 16;
    // B staging: kg = tid&15 (k-pair of 2 rows), ng = tid>>4 (col-group of 4).
    // Thread loads 2 rows x 4 cols, writes 4x bf16x2 (2x4 micro-transpose).
    // Write banks: (16*(ng&1) + 20nn + kg) mod 32 -> 2-way aliasing (~free).
    const int  kg      = tid & 15;       // 0..15
    const int  ng      = tid >> 4;       // 0..31
    const bool bactive = (ng < 28);      // 28*4 = 112 cols exactly

    const float* asrc = wb + (size_t)(m0 + ar) * CIN + ah;
    const float* bsrc = xb + (size_t)(kg * 2) * HW + n0 + ng * 4;

    f32x4 acc[2][7] = {};

    for (int k0 = 0; k0 < CIN; k0 += BK) {
        // ---- load this step's slabs into registers ----
        f32x4 a0 = *(const f32x4*)(asrc + k0);
        f32x4 a1 = *(const f32x4*)(asrc + k0 + 4);
        f32x4 a2 = *(const f32x4*)(asrc + k0 + 8);
        f32x4 a3 = *(const f32x4*)(asrc + k0 + 12);
        f32x4 r0, r1;
        if (bactive) {
            const float* bp = bsrc + (size_t)k0 * HW;
            r0 = *(const f32x4*)(bp);
            r1 = *(const f32x4*)(bp + HW);
        }

        __syncthreads();   // previous step's readers are done

        // ---- write to LDS, converting fp32 -> bf16 ----
        *(bf16x8*)&Asm[ar * LSTR + ah]     = pack8(a0, a1);
        *(bf16x8*)&Asm[ar * LSTR + ah + 8] = pack8(a2, a3);
        if (bactive) {
            #pragma unroll
            for (int nn = 0; nn < 4; nn++) {
                bf16x2 c;
                c[0] = (bf16_t)r0[nn];
                c[1] = (bf16_t)r1[nn];
                *(bf16x2*)&Bsm[(ng * 4 + nn) * LSTR + kg * 2] = c;
            }
        }

        __syncthreads();   // tile visible to all waves

        // ---- fragments + MFMA (2 m-frags x 7 n-frags) ----
        bf16x8 af[2], bfr[7];
        #pragma unroll
        for (int i = 0; i < 2; i++)
            af[i] = *(const bf16x8*)&Asm[(wm + i * 16 + l15) * LSTR + quad * 8];
        #pragma unroll
        for (int j2 = 0; j2 < 7; j2++)
            bfr[j2] = *(const bf16x8*)&Bsm[(j2 * 16 + l15) * LSTR + quad * 8];
        __builtin_amdgcn_s_setprio(1);
        #pragma unroll
        for (int i = 0; i < 2; i++)
            #pragma unroll
            for (int j2 = 0; j2 < 7; j2++)
                acc[i][j2] = __builtin_amdgcn_mfma_f32_16x16x32_bf16(af[i], bfr[j2], acc[i][j2], 0, 0, 0);
        __builtin_amdgcn_s_setprio(0);
    }

    // ---- epilogue: add bias, plain store (7*112 == 784, no guard) ----
    // C/D layout: col = lane&15, row = quad*4 + r
    float* ob = out + (size_t)batch * COUT * HW;
    #pragma unroll
    for (int j2 = 0; j2 < 7; j2++) {
        const int n = n0 + j2 * 16 + l15;
        #pragma unroll
        for (int i = 0; i < 2; i++) {
            #pragma unroll
            for (int r = 0; r < 4; r++) {
                const int m = wm + i * 16 + quad * 4 + r;
                ob[(size_t)(m0 + m) * HW + n] = acc[i][j2][r] + bias_sm[m];
            }
        }
    }
}

extern "C" void kernel_launch(void* const* d_in, const int* in_sizes, int n_in,
                              void* d_out, int out_size, void* d_ws, size_t ws_size,
                              hipStream_t stream) {
    (void)in_sizes; (void)n_in; (void)d_ws; (void)ws_size; (void)out_size;
    const float* x    = (const float*)d_in[0];
    const float* w    = (const float*)d_in[1];
    const float* bias = (const float*)d_in[2];
    float* out        = (float*)d_out;

    dim3 grid(64 * 2 * 7);   // 64 batches * 2 m-tiles * 7 n-tiles
    dim3 block(512);
    dynfc_kernel<<<grid, block, 0, stream>>>(x, w, bias, out);
}